// Round 8
// baseline (244.978 us; speedup 1.0000x reference)
//
#include <hip/hip_runtime.h>

// SoftAttention: B=4, Q=64, S=1024, H=512, fp32.
// out = [context (B*Q*H)] ++ [weights (B*Q*S)]
// ws layout: Eq [256*512]f32 @0; Ek [4096*512]f32 @+512KB;
//            Bhi/Blo (bf16 hi/lo of W, granule-major) @+8.5MB (1MB each);
//            Xhi/Xlo (bf16 hi/lo of X, granule-major) @+10.5MB (4.25MB each);
//            sraw (raw scores) @+19MB (1MB).
//
// R8: TARGETED INSTRUMENT. R7 kernels byte-identical, but proj body rep x5
// and score body rep x2 (idempotent; barrier-safe per R6 analysis). Purpose:
// disambiguate {proj_R7 still ~20us?} vs {score ~40us?} vs {both small ->
// overhead-bound}. Base time = shown / rep; Dtotal = 4*proj + score.

constexpr int kB = 4;
constexpr int kQ = 64;
constexpr int kS = 1024;
constexpr int kH = 512;

typedef short bf16x8 __attribute__((ext_vector_type(8)));
typedef float f32x4 __attribute__((ext_vector_type(4)));

__device__ __forceinline__ unsigned bf16rtn_bits(float x) {
  unsigned u = __float_as_uint(x);
  u += 0x7FFFu + ((u >> 16) & 1u);
  return u;  // hi bf16 = u>>16; its f32 bits = u & 0xFFFF0000
}

__device__ __forceinline__ void glds16(const void* g, void* l) {
  __builtin_amdgcn_global_load_lds(
      (__attribute__((address_space(1))) void*)(g),
      (__attribute__((address_space(3))) void*)(l), 16, 0, 0);
}

// ---------------------------------------------------------------------------
// Fused converter (x1, unchanged from R7).
// ---------------------------------------------------------------------------
__global__ __launch_bounds__(256) void convert_all(
    const float* __restrict__ Wk, const float* __restrict__ Wq,
    const float* __restrict__ key_, const float* __restrict__ query,
    unsigned short* __restrict__ Bhi, unsigned short* __restrict__ Blo,
    unsigned short* __restrict__ Xhi, unsigned short* __restrict__ Xlo) {
  __shared__ __align__(16) unsigned short LHi[128 * 40];
  __shared__ __align__(16) unsigned short LLo[128 * 40];
  const int bid = blockIdx.x;
  const int t = threadIdx.x;
  if (bid < 256) {
    const int gid = bid * 256 + t;
    const int c = gid & 63;
    const int g = (gid >> 6) & 3;
    const int kt = (gid >> 8) & 15;
    const int ct = (gid >> 12) & 7;
    const int mat = gid >> 15;
    const float* W = mat ? Wq : Wk;
    const float* src = W + (size_t)(kt * 32 + g * 8) * kH + ct * 64 + c;
    bf16x8 hv, lv;
#pragma unroll
    for (int j = 0; j < 8; j++) {
      float x = src[(size_t)j * kH];
      unsigned u = bf16rtn_bits(x);
      float hf = __uint_as_float(u & 0xFFFF0000u);
      unsigned v = bf16rtn_bits(x - hf);
      hv[j] = (short)(u >> 16);
      lv[j] = (short)(v >> 16);
    }
    *(bf16x8*)(Bhi + (size_t)gid * 8) = hv;
    *(bf16x8*)(Blo + (size_t)gid * 8) = lv;
    return;
  }
  const int xb = bid - 256;
  const int kt = xb & 15;
  const int rt = xb >> 4;  // 0..33
  const float* X = (rt < 32) ? (key_ + (size_t)rt * 128 * kH)
                             : (query + (size_t)(rt - 32) * 128 * kH);
  const int r = t >> 1, c0 = (t & 1) * 16;
  const float* src = X + (size_t)r * kH + kt * 32 + c0;
  bf16x8 hv0, hv1, lv0, lv1;
#pragma unroll
  for (int i = 0; i < 16; i++) {
    float x = src[i];
    unsigned u = bf16rtn_bits(x);
    float hf = __uint_as_float(u & 0xFFFF0000u);
    unsigned v = bf16rtn_bits(x - hf);
    if (i < 8) { hv0[i] = (short)(u >> 16); lv0[i] = (short)(v >> 16); }
    else       { hv1[i - 8] = (short)(u >> 16); lv1[i - 8] = (short)(v >> 16); }
  }
  *(bf16x8*)&LHi[r * 40 + c0] = hv0;
  *(bf16x8*)&LHi[r * 40 + c0 + 8] = hv1;
  *(bf16x8*)&LLo[r * 40 + c0] = lv0;
  *(bf16x8*)&LLo[r * 40 + c0 + 8] = lv1;
  __syncthreads();
  const size_t obase = (size_t)(rt * 16 + kt) * 512 * 8;
#pragma unroll
  for (int p = 0; p < 2; p++) {
    const int s = t + p * 256;
    const int rr = s & 127, g = s >> 7;
    *(uint4*)(Xhi + obase + (size_t)s * 8) = *(const uint4*)&LHi[rr * 40 + g * 8];
    *(uint4*)(Xlo + obase + (size_t)s * 8) = *(const uint4*)&LLo[rr * 40 + g * 8];
  }
}

// ---------------------------------------------------------------------------
// Projection via MFMA (R7 structure, rep x5 for measurement).
// ---------------------------------------------------------------------------
__global__ __launch_bounds__(256) void proj_mfma(
    const unsigned short* __restrict__ Xhi, const unsigned short* __restrict__ Xlo,
    const unsigned short* __restrict__ Bhi, const unsigned short* __restrict__ Blo,
    const float* __restrict__ bk, const float* __restrict__ bq,
    float* __restrict__ Ek, float* __restrict__ Eq) {
  __shared__ __align__(16) unsigned short AhiL[2][2048];
  __shared__ __align__(16) unsigned short AloL[2][2048];
  __shared__ __align__(16) unsigned short BhiL[2][2048];
  __shared__ __align__(16) unsigned short BloL[2][2048];

  const int bid = blockIdx.y * 8 + blockIdx.x;
  int ct, rt;
  if (bid < 512) {
    ct = (bid >> 3) & 7;
    rt = (bid & 7) + 8 * (bid >> 6);
  } else {
    const int tb = bid - 512;
    ct = tb >> 2;
    rt = 64 + (tb & 3);
  }

  const int mat = (rt >= 64) ? 1 : 0;
  const float* bias = mat ? bq : bk;
  float* Y = mat ? (Eq + (size_t)(rt - 64) * 64 * kH)
                 : (Ek + (size_t)rt * 64 * kH);

  const int t = threadIdx.x;
  const int rt128 = rt >> 1, hhalf = rt & 1;
  const int ga_slot = ((t >> 6) << 7) + (hhalf << 6) + (t & 63);
  const unsigned short* gah = Xhi + ((size_t)(rt128 * 16) * 512 + ga_slot) * 8;
  const unsigned short* gal = Xlo + ((size_t)(rt128 * 16) * 512 + ga_slot) * 8;
  const unsigned short* gbh = Bhi + (((size_t)(mat * 8 + ct) * 16) * 256 + t) * 8;
  const unsigned short* gbl = Blo + (((size_t)(mat * 8 + ct) * 16) * 256 + t) * 8;

  auto stage = [&](int buf, int kt2) {
    glds16(gah + (size_t)kt2 * 512 * 8, &AhiL[buf][t * 8]);
    glds16(gal + (size_t)kt2 * 512 * 8, &AloL[buf][t * 8]);
    glds16(gbh + (size_t)kt2 * 256 * 8, &BhiL[buf][t * 8]);
    glds16(gbl + (size_t)kt2 * 256 * 8, &BloL[buf][t * 8]);
  };

  const int l = t & 63, lg = l >> 4, lr = l & 15;
  const int wv = t >> 6, wm = wv >> 1, wn = wv & 1;
  const int oa0 = (lg * 64 + wm * 32 + lr) * 8;
  const int ob0 = (lg * 64 + wn * 32 + lr) * 8;

#pragma unroll 1
  for (int rep = 0; rep < 5; ++rep) {
    asm volatile("" ::: "memory");
    f32x4 acc[2][2];
#pragma unroll
    for (int m = 0; m < 2; m++)
#pragma unroll
      for (int n = 0; n < 2; n++) acc[m][n] = {0.f, 0.f, 0.f, 0.f};

    stage(0, 0);
    __syncthreads();

    int buf = 0;
    for (int kt2 = 0; kt2 < 16; kt2++) {
      if (kt2 < 15) stage(buf ^ 1, kt2 + 1);

      const unsigned short* Ah = AhiL[buf];
      const unsigned short* Al = AloL[buf];
      const unsigned short* Bh = BhiL[buf];
      const unsigned short* Bl = BloL[buf];
      bf16x8 ah[2], al[2], bh[2], bl[2];
#pragma unroll
      for (int m = 0; m < 2; m++) {
        ah[m] = *(const bf16x8*)(Ah + oa0 + m * 128);
        al[m] = *(const bf16x8*)(Al + oa0 + m * 128);
      }
#pragma unroll
      for (int n = 0; n < 2; n++) {
        bh[n] = *(const bf16x8*)(Bh + ob0 + n * 128);
        bl[n] = *(const bf16x8*)(Bl + ob0 + n * 128);
      }
#pragma unroll
      for (int m = 0; m < 2; m++)
#pragma unroll
        for (int n = 0; n < 2; n++) {
          acc[m][n] = __builtin_amdgcn_mfma_f32_16x16x32_bf16(ah[m], bh[n], acc[m][n], 0, 0, 0);
          acc[m][n] = __builtin_amdgcn_mfma_f32_16x16x32_bf16(al[m], bh[n], acc[m][n], 0, 0, 0);
          acc[m][n] = __builtin_amdgcn_mfma_f32_16x16x32_bf16(ah[m], bl[n], acc[m][n], 0, 0, 0);
        }

      __syncthreads();
      buf ^= 1;
    }

    const int col0 = ct * 64 + wn * 32 + lr;
    const float b0 = bias[col0];
    const float b1 = bias[col0 + 16];
#pragma unroll
    for (int m = 0; m < 2; m++) {
      const int row0 = wm * 32 + m * 16 + lg * 4;
#pragma unroll
      for (int jj = 0; jj < 4; jj++) {
        float* y = Y + (size_t)(row0 + jj) * kH;
        y[col0]      = __expf(2.f * (acc[m][0][jj] + b0));
        y[col0 + 16] = __expf(2.f * (acc[m][1][jj] + b1));
      }
    }
  }
}

// ---------------------------------------------------------------------------
// Scores (R3/R7 structure, rep x2 for measurement).
// ---------------------------------------------------------------------------
__global__ __launch_bounds__(256) void score_kernel(
    const float* __restrict__ Eq, const float* __restrict__ Ek,
    const float* __restrict__ we, float* __restrict__ sraw) {
  __shared__ __align__(16) float EkL[2][64 * 64];

  const int qt = blockIdx.x, st = blockIdx.y, b = blockIdx.z;
  const int t = threadIdx.x, lane = t & 63;
  const int wvu = __builtin_amdgcn_readfirstlane(t >> 6);  // uniform wave id
  const int s0 = st * 64;
  const int q0g = b * kQ + qt * 8;
  const int qA = wvu * 2;

  const float4* we4 = (const float4*)we;
  const float4* qa4 = (const float4*)(Eq + (size_t)(q0g + qA) * kH);
  const float4* qb4 = (const float4*)(Eq + (size_t)(q0g + qA + 1) * kH);

  const int er = t >> 4;
  const int ej = t & 15;
  const float* ekg = Ek + (size_t)(b * kS + s0 + er) * kH + ej * 4;
  float4 pk[4];
  auto gload = [&](int c) {
#pragma unroll
    for (int i = 0; i < 4; i++)
      pk[i] = *(const float4*)(ekg + (size_t)(16 * i) * kH + c * 64);
  };
  auto lwrite = [&](int buf) {
#pragma unroll
    for (int i = 0; i < 4; i++) {
      const int row = er + 16 * i;
      *(float4*)(&EkL[buf][row * 64 + ((ej ^ (row & 15)) << 2)]) = pk[i];
    }
  };

#pragma unroll 1
  for (int rep = 0; rep < 2; ++rep) {
    asm volatile("" ::: "memory");
    float4 u0 = we4[lane * 2], u1 = we4[lane * 2 + 1];
    float wsum = u0.x + u0.y + u0.z + u0.w + u1.x + u1.y + u1.z + u1.w;
#pragma unroll
    for (int off = 32; off; off >>= 1) wsum += __shfl_xor(wsum, off);

    gload(0);
    lwrite(0);
    __syncthreads();

    float accA = 0.f, accB = 0.f;
    const int sw = lane & 15;

    for (int c = 0; c < 8; c++) {
      if (c < 7) gload(c + 1);
      const float* ekb = &EkL[c & 1][lane * 64];
#pragma unroll 4
      for (int g = 0; g < 16; g++) {
        float4 ek = *(const float4*)(ekb + ((g ^ sw) << 2));
        float4 w = we4[c * 16 + g];
        float4 qa = qa4[c * 16 + g];
        float4 qb = qb4[c * 16 + g];
        {
          float a1 = fmaf(qa.x, ek.x, 1.f), b1 = fmaf(qa.y, ek.y, 1.f);
          float n1 = fmaf(w.y, a1, w.x * b1);
          accA = fmaf(n1, __builtin_amdgcn_rcpf(a1 * b1), accA);
          float a2 = fmaf(qa.z, ek.z, 1.f), b2 = fmaf(qa.w, ek.w, 1.f);
          float n2 = fmaf(w.w, a2, w.z * b2);
          accA = fmaf(n2, __builtin_amdgcn_rcpf(a2 * b2), accA);
        }
        {
          float a1 = fmaf(qb.x, ek.x, 1.f), b1 = fmaf(qb.y, ek.y, 1.f);
          float n1 = fmaf(w.y, a1, w.x * b1);
          accB = fmaf(n1, __builtin_amdgcn_rcpf(a1 * b1), accB);
          float a2 = fmaf(qb.z, ek.z, 1.f), b2 = fmaf(qb.w, ek.w, 1.f);
          float n2 = fmaf(w.w, a2, w.z * b2);
          accB = fmaf(n2, __builtin_amdgcn_rcpf(a2 * b2), accB);
        }
      }
      if (c < 7) {
        __syncthreads();
        lwrite((c + 1) & 1);
        __syncthreads();
      }
    }

    sraw[(size_t)(q0g + qA + 0) * kS + s0 + lane] = fmaf(-2.f, accA, wsum);
    sraw[(size_t)(q0g + qA + 1) * kS + s0 + lane] = fmaf(-2.f, accB, wsum);
    __syncthreads();  // protect EkL across reps
  }
}

// ---------------------------------------------------------------------------
// Fused softmax + context + reduce (x1, unchanged from R7).
// ---------------------------------------------------------------------------
__global__ __launch_bounds__(256) void ctx_fused(
    const float* __restrict__ sraw, const float* __restrict__ value,
    float* __restrict__ wout, float* __restrict__ ctx) {
  __shared__ __align__(16) float wt[4][1024];
  __shared__ __align__(16) float parts[4][4][128];
  const int bid = blockIdx.x;
  const int qc = bid >> 4, b = (bid >> 2) & 3, hc = bid & 3;
  const int t = threadIdx.x, wv = t >> 6, lane = t & 63;
  const int grow = b * kQ + qc * 4 + wv;

  const float4* row4 = (const float4*)(sraw + (size_t)grow * kS);
  float4 v[4];
#pragma unroll
  for (int j = 0; j < 4; j++) v[j] = row4[lane + 64 * j];
  float m = -1e30f;
#pragma unroll
  for (int j = 0; j < 4; j++)
    m = fmaxf(m, fmaxf(fmaxf(v[j].x, v[j].y), fmaxf(v[j].z, v[j].w)));
#pragma unroll
  for (int off = 32; off; off >>= 1) m = fmaxf(m, __shfl_xor(m, off));
  float sum = 0.f;
#pragma unroll
  for (int j = 0; j < 4; j++) {
    v[j].x = __expf(v[j].x - m); v[j].y = __expf(v[j].y - m);
    v[j].z = __expf(v[j].z - m); v[j].w = __expf(v[j].w - m);
    sum += v[j].x + v[j].y + v[j].z + v[j].w;
  }
#pragma unroll
  for (int off = 32; off; off >>= 1) sum += __shfl_xor(sum, off);
  const float inv = 1.f / sum;
  float4* wrow = (float4*)&wt[wv][0];
  float4* gw = (float4*)(wout + (size_t)grow * kS);
#pragma unroll
  for (int j = 0; j < 4; j++) {
    v[j].x *= inv; v[j].y *= inv; v[j].z *= inv; v[j].w *= inv;
    wrow[lane + 64 * j] = v[j];
    if (hc == 0) gw[lane + 64 * j] = v[j];
  }
  __syncthreads();

  const float* vbase =
      value + ((size_t)b * kS + wv * 256) * kH + hc * 128 + lane * 2;
  float2 acc[4];
#pragma unroll
  for (int q = 0; q < 4; q++) acc[q] = {0.f, 0.f};
#pragma unroll 2
  for (int s4 = 0; s4 < 64; s4++) {
    float4 wq[4];
#pragma unroll
    for (int q = 0; q < 4; q++)
      wq[q] = *(const float4*)&wt[q][wv * 256 + s4 * 4];
#pragma unroll
    for (int u = 0; u < 4; u++) {
      const float2 vv = *(const float2*)(vbase + (size_t)(s4 * 4 + u) * kH);
      const float w0 = ((const float*)&wq[0])[u];
      const float w1 = ((const float*)&wq[1])[u];
      const float w2 = ((const float*)&wq[2])[u];
      const float w3 = ((const float*)&wq[3])[u];
      acc[0].x = fmaf(w0, vv.x, acc[0].x); acc[0].y = fmaf(w0, vv.y, acc[0].y);
      acc[1].x = fmaf(w1, vv.x, acc[1].x); acc[1].y = fmaf(w1, vv.y, acc[1].y);
      acc[2].x = fmaf(w2, vv.x, acc[2].x); acc[2].y = fmaf(w2, vv.y, acc[2].y);
      acc[3].x = fmaf(w3, vv.x, acc[3].x); acc[3].y = fmaf(w3, vv.y, acc[3].y);
    }
  }
#pragma unroll
  for (int q = 0; q < 4; q++)
    *(float2*)&parts[wv][q][lane * 2] = acc[q];
  __syncthreads();

  const int q = t >> 6, hp = t & 63;
  float2 r = {0.f, 0.f};
#pragma unroll
  for (int w = 0; w < 4; w++) {
    const float2 p2 = *(const float2*)&parts[w][q][hp * 2];
    r.x += p2.x; r.y += p2.y;
  }
  *(float2*)(ctx + (size_t)(b * kQ + qc * 4 + q) * kH + hc * 128 + hp * 2) = r;
}

extern "C" void kernel_launch(void* const* d_in, const int* in_sizes, int n_in,
                              void* d_out, int out_size, void* d_ws,
                              size_t ws_size, hipStream_t stream) {
  const float* query = (const float*)d_in[0];
  const float* key_  = (const float*)d_in[1];
  const float* value = (const float*)d_in[2];
  const float* Wq    = (const float*)d_in[3];
  const float* bq    = (const float*)d_in[4];
  const float* Wk    = (const float*)d_in[5];
  const float* bk    = (const float*)d_in[6];
  const float* we    = (const float*)d_in[7];
  // be (d_in[8]) cancels in softmax.

  float* ctx  = (float*)d_out;                         // [256*512]
  float* wout = (float*)d_out + (size_t)kB * kQ * kH;  // [256*1024]

  float* Eq = (float*)d_ws;                            // 512 KB
  float* Ek = Eq + (size_t)kB * kQ * kH;               // 8 MB
  unsigned short* Bhi =
      (unsigned short*)((char*)d_ws + (size_t)(kB * kQ * kH + kB * kS * kH) * 4);
  unsigned short* Blo = Bhi + (size_t)2 * 8 * 16 * 256 * 8;  // +1MB
  unsigned short* Xhi = Blo + (size_t)2 * 8 * 16 * 256 * 8;  // +1MB
  unsigned short* Xlo = Xhi + (size_t)34 * 16 * 512 * 8;     // +4.25MB
  float* sraw = (float*)(Xlo + (size_t)34 * 16 * 512 * 8);   // +4.25MB -> 1MB

  convert_all<<<800, 256, 0, stream>>>(Wk, Wq, key_, query, Bhi, Blo, Xhi, Xlo);
  proj_mfma<<<dim3(8, 68), 256, 0, stream>>>(Xhi, Xlo, Bhi, Blo, bk, bq, Ek, Eq);
  score_kernel<<<dim3(8, 16, 4), 256, 0, stream>>>(Eq, Ek, we, sraw);
  ctx_fused<<<256, 256, 0, stream>>>(sraw, value, wout, ctx);
}

// Round 9
// 139.111 us; speedup vs baseline: 1.7610x; 1.7610x over previous
//
#include <hip/hip_runtime.h>

// SoftAttention: B=4, Q=64, S=1024, H=512, fp32.
// out = [context (B*Q*H)] ++ [weights (B*Q*S)]
// ws: Eq [256*512]f32 @0; sraw4 [4][256][1024]f32 @+512KB (inside old Ek区);
//     Bhi/Blo @+8.5MB (1MB each); Xhi/Xlo @+10.5MB (4.25MB each);
//     EkT [4][512][1024]f32 @+19MB (8MB).
//
// R8 measured: proj_R7 = 18.2us (MfmaUtil 14.5, VALUBusy 6, Occ 12 -> barrier
//   drains the just-issued prefetch every K-step); score = 22.9us (Dtotal eq).
// R9: (a) proj: 3-buffer pipeline, counted s_waitcnt vmcnt(4) + raw s_barrier
//     (one barrier/iter, prefetch 2 ahead, never drain) [T3/T4, m218];
//     (b) proj epilogue writes EkT (LDS-transposed, coalesced) instead of Ek;
//     (c) score: no LDS/barriers; lane=s coalesced EkT loads (vmcnt) + uniform
//     scalar q/w loads (lgkmcnt, separate counter); unit = 2q x 64s x 128h ->
//     8192 waves (~100% occupancy, was 25%); partials sraw4[hq];
//     (d) ctx_fused Phase A sums the 4 h-quarter partials.

constexpr int kB = 4;
constexpr int kQ = 64;
constexpr int kS = 1024;
constexpr int kH = 512;

typedef short bf16x8 __attribute__((ext_vector_type(8)));
typedef float f32x4 __attribute__((ext_vector_type(4)));

__device__ __forceinline__ unsigned bf16rtn_bits(float x) {
  unsigned u = __float_as_uint(x);
  u += 0x7FFFu + ((u >> 16) & 1u);
  return u;  // hi bf16 = u>>16; its f32 bits = u & 0xFFFF0000
}

__device__ __forceinline__ void glds16(const void* g, void* l) {
  __builtin_amdgcn_global_load_lds(
      (__attribute__((address_space(1))) void*)(g),
      (__attribute__((address_space(3))) void*)(l), 16, 0, 0);
}

// ---------------------------------------------------------------------------
// Fused converter (unchanged from R7).
// ---------------------------------------------------------------------------
__global__ __launch_bounds__(256) void convert_all(
    const float* __restrict__ Wk, const float* __restrict__ Wq,
    const float* __restrict__ key_, const float* __restrict__ query,
    unsigned short* __restrict__ Bhi, unsigned short* __restrict__ Blo,
    unsigned short* __restrict__ Xhi, unsigned short* __restrict__ Xlo) {
  __shared__ __align__(16) unsigned short LHi[128 * 40];
  __shared__ __align__(16) unsigned short LLo[128 * 40];
  const int bid = blockIdx.x;
  const int t = threadIdx.x;
  if (bid < 256) {
    const int gid = bid * 256 + t;
    const int c = gid & 63;
    const int g = (gid >> 6) & 3;
    const int kt = (gid >> 8) & 15;
    const int ct = (gid >> 12) & 7;
    const int mat = gid >> 15;
    const float* W = mat ? Wq : Wk;
    const float* src = W + (size_t)(kt * 32 + g * 8) * kH + ct * 64 + c;
    bf16x8 hv, lv;
#pragma unroll
    for (int j = 0; j < 8; j++) {
      float x = src[(size_t)j * kH];
      unsigned u = bf16rtn_bits(x);
      float hf = __uint_as_float(u & 0xFFFF0000u);
      unsigned v = bf16rtn_bits(x - hf);
      hv[j] = (short)(u >> 16);
      lv[j] = (short)(v >> 16);
    }
    *(bf16x8*)(Bhi + (size_t)gid * 8) = hv;
    *(bf16x8*)(Blo + (size_t)gid * 8) = lv;
    return;
  }
  const int xb = bid - 256;
  const int kt = xb & 15;
  const int rt = xb >> 4;  // 0..33
  const float* X = (rt < 32) ? (key_ + (size_t)rt * 128 * kH)
                             : (query + (size_t)(rt - 32) * 128 * kH);
  const int r = t >> 1, c0 = (t & 1) * 16;
  const float* src = X + (size_t)r * kH + kt * 32 + c0;
  bf16x8 hv0, hv1, lv0, lv1;
#pragma unroll
  for (int i = 0; i < 16; i++) {
    float x = src[i];
    unsigned u = bf16rtn_bits(x);
    float hf = __uint_as_float(u & 0xFFFF0000u);
    unsigned v = bf16rtn_bits(x - hf);
    if (i < 8) { hv0[i] = (short)(u >> 16); lv0[i] = (short)(v >> 16); }
    else       { hv1[i - 8] = (short)(u >> 16); lv1[i - 8] = (short)(v >> 16); }
  }
  *(bf16x8*)&LHi[r * 40 + c0] = hv0;
  *(bf16x8*)&LHi[r * 40 + c0 + 8] = hv1;
  *(bf16x8*)&LLo[r * 40 + c0] = lv0;
  *(bf16x8*)&LLo[r * 40 + c0 + 8] = lv1;
  __syncthreads();
  const size_t obase = (size_t)(rt * 16 + kt) * 512 * 8;
#pragma unroll
  for (int p = 0; p < 2; p++) {
    const int s = t + p * 256;
    const int rr = s & 127, g = s >> 7;
    *(uint4*)(Xhi + obase + (size_t)s * 8) = *(const uint4*)&LHi[rr * 40 + g * 8];
    *(uint4*)(Xlo + obase + (size_t)s * 8) = *(const uint4*)&LLo[rr * 40 + g * 8];
  }
}

// ---------------------------------------------------------------------------
// Projection via MFMA. E = exp(2*(X @ W + bias)).
// 64x64 tile, 256 thr = 4 waves (2m x 2n), 12 MFMA/K-step, BK=32.
// 3-buffer LDS rotation, counted s_waitcnt vmcnt(4) + raw s_barrier (ONE
// barrier per K-step, prefetch 2 ahead, never drained to 0 in-loop).
// mat==0 (key): epilogue LDS-transposes the 64x64 E-tile and writes EkT
// [b][h][s] coalesced. mat==1 (query): row-major Eq as before.
// grid = (8,68) XCD-swizzled as in R7.
// ---------------------------------------------------------------------------
__global__ __launch_bounds__(256) void proj_mfma(
    const unsigned short* __restrict__ Xhi, const unsigned short* __restrict__ Xlo,
    const unsigned short* __restrict__ Bhi, const unsigned short* __restrict__ Blo,
    const float* __restrict__ bk, const float* __restrict__ bq,
    float* __restrict__ EkT, float* __restrict__ Eq) {
  __shared__ __align__(16) unsigned short AhiL[3][2048];
  __shared__ __align__(16) unsigned short AloL[3][2048];
  __shared__ __align__(16) unsigned short BhiL[3][2048];
  __shared__ __align__(16) unsigned short BloL[3][2048];
  __shared__ __align__(16) float T[64][65];  // +1 pad: conflict-free transpose

  const int bid = blockIdx.y * 8 + blockIdx.x;
  int ct, rt;
  if (bid < 512) {
    ct = (bid >> 3) & 7;
    rt = (bid & 7) + 8 * (bid >> 6);
  } else {
    const int tb = bid - 512;
    ct = tb >> 2;
    rt = 64 + (tb & 3);
  }

  const int mat = (rt >= 64) ? 1 : 0;
  const float* bias = mat ? bq : bk;

  const int t = threadIdx.x;
  const int rt128 = rt >> 1, hhalf = rt & 1;
  const int ga_slot = ((t >> 6) << 7) + (hhalf << 6) + (t & 63);
  const unsigned short* gah = Xhi + ((size_t)(rt128 * 16) * 512 + ga_slot) * 8;
  const unsigned short* gal = Xlo + ((size_t)(rt128 * 16) * 512 + ga_slot) * 8;
  const unsigned short* gbh = Bhi + (((size_t)(mat * 8 + ct) * 16) * 256 + t) * 8;
  const unsigned short* gbl = Blo + (((size_t)(mat * 8 + ct) * 16) * 256 + t) * 8;

  auto stage = [&](int buf, int kt2) {
    glds16(gah + (size_t)kt2 * 512 * 8, &AhiL[buf][t * 8]);
    glds16(gal + (size_t)kt2 * 512 * 8, &AloL[buf][t * 8]);
    glds16(gbh + (size_t)kt2 * 256 * 8, &BhiL[buf][t * 8]);
    glds16(gbl + (size_t)kt2 * 256 * 8, &BloL[buf][t * 8]);
  };

  const int l = t & 63, lg = l >> 4, lr = l & 15;
  const int wv = t >> 6, wm = wv >> 1, wn = wv & 1;
  const int oa0 = (lg * 64 + wm * 32 + lr) * 8;
  const int ob0 = (lg * 64 + wn * 32 + lr) * 8;

  f32x4 acc[2][2];
#pragma unroll
  for (int m = 0; m < 2; m++)
#pragma unroll
    for (int n = 0; n < 2; n++) acc[m][n] = {0.f, 0.f, 0.f, 0.f};

  stage(0, 0);
  stage(1, 1);

#pragma unroll
  for (int kt2 = 0; kt2 < 16; kt2++) {
    // Counted wait: the 4 newest (next-tile prefetch) stay in flight.
    if (kt2 < 15) asm volatile("s_waitcnt vmcnt(4)" ::: "memory");
    else          asm volatile("s_waitcnt vmcnt(0)" ::: "memory");
    __builtin_amdgcn_s_barrier();
    __builtin_amdgcn_sched_barrier(0);

    const int rb = kt2 % 3;
    const unsigned short* Ah = AhiL[rb];
    const unsigned short* Al = AloL[rb];
    const unsigned short* Bh = BhiL[rb];
    const unsigned short* Bl = BloL[rb];
    bf16x8 ah[2], al[2], bh[2], bl[2];
#pragma unroll
    for (int m = 0; m < 2; m++) {
      ah[m] = *(const bf16x8*)(Ah + oa0 + m * 128);
      al[m] = *(const bf16x8*)(Al + oa0 + m * 128);
    }
#pragma unroll
    for (int n = 0; n < 2; n++) {
      bh[n] = *(const bf16x8*)(Bh + ob0 + n * 128);
      bl[n] = *(const bf16x8*)(Bl + ob0 + n * 128);
    }
    if (kt2 < 14) stage((kt2 + 2) % 3, kt2 + 2);  // overlaps MFMAs below
#pragma unroll
    for (int m = 0; m < 2; m++)
#pragma unroll
      for (int n = 0; n < 2; n++) {
        acc[m][n] = __builtin_amdgcn_mfma_f32_16x16x32_bf16(ah[m], bh[n], acc[m][n], 0, 0, 0);
        acc[m][n] = __builtin_amdgcn_mfma_f32_16x16x32_bf16(al[m], bh[n], acc[m][n], 0, 0, 0);
        acc[m][n] = __builtin_amdgcn_mfma_f32_16x16x32_bf16(ah[m], bl[n], acc[m][n], 0, 0, 0);
      }
    // Pin MFMAs/ds_reads above the next barrier (rule #18 analog).
    __builtin_amdgcn_sched_barrier(0);
  }

  const int colL = wn * 32 + lr;           // local col 0..63 (h within tile)
  const int col0 = ct * 64 + colL;
  const float b0 = bias[col0];
  const float b1 = bias[col0 + 16];

  if (mat == 0) {
    // E tile -> LDS -> transposed coalesced EkT writes.
#pragma unroll
    for (int m = 0; m < 2; m++) {
      const int row0 = wm * 32 + m * 16 + lg * 4;
#pragma unroll
      for (int jj = 0; jj < 4; jj++) {
        T[row0 + jj][colL]      = __expf(2.f * (acc[m][0][jj] + b0));
        T[row0 + jj][colL + 16] = __expf(2.f * (acc[m][1][jj] + b1));
      }
    }
    __syncthreads();
    const int sl = t & 63;              // s within tile (lane -> coalesced)
    const int cb = (t >> 6) * 16;       // col block
    const int R = rt * 64 + sl;         // global key row
    const int bb = R >> 10, ss = R & 1023;
    float* outp = EkT + ((size_t)(bb * kH + ct * 64)) * kS + ss;
#pragma unroll
    for (int i = 0; i < 16; i++)
      outp[(size_t)(cb + i) * kS] = T[sl][cb + i];
  } else {
    float* Y = Eq + (size_t)(rt - 64) * 64 * kH;
#pragma unroll
    for (int m = 0; m < 2; m++) {
      const int row0 = wm * 32 + m * 16 + lg * 4;
#pragma unroll
      for (int jj = 0; jj < 4; jj++) {
        float* y = Y + (size_t)(row0 + jj) * kH;
        y[col0]      = __expf(2.f * (acc[m][0][jj] + b0));
        y[col0 + 16] = __expf(2.f * (acc[m][1][jj] + b1));
      }
    }
  }
}

// ---------------------------------------------------------------------------
// Scores (partials) -> sraw4[hq][bq][s].  No LDS, no barriers.
// Unit = wave = (b, q-pair, 64 s, 128 h-quarter): 8192 units = 4096 blocks
// x 128 thr (2 independent waves/block) -> ~full occupancy.
// partial = sum_{h in q} we_h - 2 * sum we_h * rcp(1 + Eq*EkT), rcps paired.
// EkT loads: lane = s, coalesced dwords (vmcnt). q/w rows: uniform scalar
// loads (lgkmcnt) - separate counters, no false serialization.
// ---------------------------------------------------------------------------
__global__ __launch_bounds__(128) void score_kernel(
    const float* __restrict__ Eq, const float* __restrict__ EkT,
    const float* __restrict__ we, float* __restrict__ sraw4) {
  const int t = threadIdx.x, lane = t & 63;
  const int wvu = __builtin_amdgcn_readfirstlane(t >> 6);
  const int u = blockIdx.x * 2 + wvu;
  const int hq = u & 3, st = (u >> 2) & 15, qp = (u >> 6) & 31, b = u >> 11;
  const int s = st * 64 + lane;
  const int q0g = b * kQ + qp * 2;
  const int h0 = hq * 128;

  const float4* w4 = (const float4*)(we + h0);
  const float4* qa4 = (const float4*)(Eq + (size_t)q0g * kH + h0);
  const float4* qb4 = (const float4*)(Eq + (size_t)(q0g + 1) * kH + h0);
  const float* ek = EkT + ((size_t)(b * kH + h0)) * kS + s;

  float accA = 0.f, accB = 0.f, wsum = 0.f;
#pragma unroll 4
  for (int g = 0; g < 32; g++) {
    const float4 w = w4[g];
    const float4 qa = qa4[g];
    const float4 qb = qb4[g];
    const float e0 = ek[(size_t)(4 * g + 0) * kS];
    const float e1 = ek[(size_t)(4 * g + 1) * kS];
    const float e2 = ek[(size_t)(4 * g + 2) * kS];
    const float e3 = ek[(size_t)(4 * g + 3) * kS];
    wsum += w.x + w.y + w.z + w.w;
    {
      float a1 = fmaf(qa.x, e0, 1.f), c1 = fmaf(qa.y, e1, 1.f);
      accA = fmaf(fmaf(w.y, a1, w.x * c1), __builtin_amdgcn_rcpf(a1 * c1), accA);
      float a2 = fmaf(qa.z, e2, 1.f), c2 = fmaf(qa.w, e3, 1.f);
      accA = fmaf(fmaf(w.w, a2, w.z * c2), __builtin_amdgcn_rcpf(a2 * c2), accA);
    }
    {
      float a1 = fmaf(qb.x, e0, 1.f), c1 = fmaf(qb.y, e1, 1.f);
      accB = fmaf(fmaf(w.y, a1, w.x * c1), __builtin_amdgcn_rcpf(a1 * c1), accB);
      float a2 = fmaf(qb.z, e2, 1.f), c2 = fmaf(qb.w, e3, 1.f);
      accB = fmaf(fmaf(w.w, a2, w.z * c2), __builtin_amdgcn_rcpf(a2 * c2), accB);
    }
  }

  float* plane = sraw4 + (size_t)hq * kB * kQ * kS;
  plane[(size_t)(q0g + 0) * kS + s] = fmaf(-2.f, accA, wsum);
  plane[(size_t)(q0g + 1) * kS + s] = fmaf(-2.f, accB, wsum);
}

// ---------------------------------------------------------------------------
// Fused softmax + context + reduce.  Phase A now sums the 4 h-quarter score
// partials before softmax.  Otherwise unchanged from R7.
// ---------------------------------------------------------------------------
__global__ __launch_bounds__(256) void ctx_fused(
    const float* __restrict__ sraw4, const float* __restrict__ value,
    float* __restrict__ wout, float* __restrict__ ctx) {
  __shared__ __align__(16) float wt[4][1024];
  __shared__ __align__(16) float parts[4][4][128];
  const int bid = blockIdx.x;
  const int qc = bid >> 4, b = (bid >> 2) & 3, hc = bid & 3;
  const int t = threadIdx.x, wv = t >> 6, lane = t & 63;
  const int grow = b * kQ + qc * 4 + wv;

  const size_t plane = (size_t)kB * kQ * kS / 4;  // float4 stride per hq plane
  const float4* r0 = (const float4*)(sraw4) + (size_t)grow * (kS / 4);
  const float4* r1 = r0 + plane;
  const float4* r2 = r1 + plane;
  const float4* r3 = r2 + plane;
  float4 v[4];
#pragma unroll
  for (int j = 0; j < 4; j++) {
    const int idx = lane + 64 * j;
    float4 p0 = r0[idx], p1 = r1[idx], p2 = r2[idx], p3 = r3[idx];
    v[j].x = (p0.x + p1.x) + (p2.x + p3.x);
    v[j].y = (p0.y + p1.y) + (p2.y + p3.y);
    v[j].z = (p0.z + p1.z) + (p2.z + p3.z);
    v[j].w = (p0.w + p1.w) + (p2.w + p3.w);
  }
  float m = -1e30f;
#pragma unroll
  for (int j = 0; j < 4; j++)
    m = fmaxf(m, fmaxf(fmaxf(v[j].x, v[j].y), fmaxf(v[j].z, v[j].w)));
#pragma unroll
  for (int off = 32; off; off >>= 1) m = fmaxf(m, __shfl_xor(m, off));
  float sum = 0.f;
#pragma unroll
  for (int j = 0; j < 4; j++) {
    v[j].x = __expf(v[j].x - m); v[j].y = __expf(v[j].y - m);
    v[j].z = __expf(v[j].z - m); v[j].w = __expf(v[j].w - m);
    sum += v[j].x + v[j].y + v[j].z + v[j].w;
  }
#pragma unroll
  for (int off = 32; off; off >>= 1) sum += __shfl_xor(sum, off);
  const float inv = 1.f / sum;
  float4* wrow = (float4*)&wt[wv][0];
  float4* gw = (float4*)(wout + (size_t)grow * kS);
#pragma unroll
  for (int j = 0; j < 4; j++) {
    v[j].x *= inv; v[j].y *= inv; v[j].z *= inv; v[j].w *= inv;
    wrow[lane + 64 * j] = v[j];
    if (hc == 0) gw[lane + 64 * j] = v[j];
  }
  __syncthreads();

  const float* vbase =
      value + ((size_t)b * kS + wv * 256) * kH + hc * 128 + lane * 2;
  float2 acc[4];
#pragma unroll
  for (int q = 0; q < 4; q++) acc[q] = {0.f, 0.f};
#pragma unroll 2
  for (int s4 = 0; s4 < 64; s4++) {
    float4 wq[4];
#pragma unroll
    for (int q = 0; q < 4; q++)
      wq[q] = *(const float4*)&wt[q][wv * 256 + s4 * 4];
#pragma unroll
    for (int uu = 0; uu < 4; uu++) {
      const float2 vv = *(const float2*)(vbase + (size_t)(s4 * 4 + uu) * kH);
      const float w0 = ((const float*)&wq[0])[uu];
      const float w1 = ((const float*)&wq[1])[uu];
      const float w2 = ((const float*)&wq[2])[uu];
      const float w3 = ((const float*)&wq[3])[uu];
      acc[0].x = fmaf(w0, vv.x, acc[0].x); acc[0].y = fmaf(w0, vv.y, acc[0].y);
      acc[1].x = fmaf(w1, vv.x, acc[1].x); acc[1].y = fmaf(w1, vv.y, acc[1].y);
      acc[2].x = fmaf(w2, vv.x, acc[2].x); acc[2].y = fmaf(w2, vv.y, acc[2].y);
      acc[3].x = fmaf(w3, vv.x, acc[3].x); acc[3].y = fmaf(w3, vv.y, acc[3].y);
    }
  }
#pragma unroll
  for (int q = 0; q < 4; q++)
    *(float2*)&parts[wv][q][lane * 2] = acc[q];
  __syncthreads();

  const int q = t >> 6, hp = t & 63;
  float2 r = {0.f, 0.f};
#pragma unroll
  for (int w = 0; w < 4; w++) {
    const float2 p2 = *(const float2*)&parts[w][q][hp * 2];
    r.x += p2.x; r.y += p2.y;
  }
  *(float2*)(ctx + (size_t)(b * kQ + qc * 4 + q) * kH + hc * 128 + hp * 2) = r;
}

extern "C" void kernel_launch(void* const* d_in, const int* in_sizes, int n_in,
                              void* d_out, int out_size, void* d_ws,
                              size_t ws_size, hipStream_t stream) {
  const float* query = (const float*)d_in[0];
  const float* key_  = (const float*)d_in[1];
  const float* value = (const float*)d_in[2];
  const float* Wq    = (const float*)d_in[3];
  const float* bq    = (const float*)d_in[4];
  const float* Wk    = (const float*)d_in[5];
  const float* bk    = (const float*)d_in[6];
  const float* we    = (const float*)d_in[7];
  // be (d_in[8]) cancels in softmax.

  float* ctx  = (float*)d_out;                         // [256*512]
  float* wout = (float*)d_out + (size_t)kB * kQ * kH;  // [256*1024]

  float* Eq    = (float*)d_ws;                          // 512 KB
  float* sraw4 = Eq + (size_t)kB * kQ * kH;             // 4 MB (old Ek region)
  unsigned short* Bhi =
      (unsigned short*)((char*)d_ws + (size_t)(kB * kQ * kH + kB * kS * kH) * 4);
  unsigned short* Blo = Bhi + (size_t)2 * 8 * 16 * 256 * 8;  // +1MB
  unsigned short* Xhi = Blo + (size_t)2 * 8 * 16 * 256 * 8;  // +1MB
  unsigned short* Xlo = Xhi + (size_t)34 * 16 * 512 * 8;     // +4.25MB
  float* EkT = (float*)(Xlo + (size_t)34 * 16 * 512 * 8);    // +4.25MB -> 8MB

  convert_all<<<800, 256, 0, stream>>>(Wk, Wq, key_, query, Bhi, Blo, Xhi, Xlo);
  proj_mfma<<<dim3(8, 68), 256, 0, stream>>>(Xhi, Xlo, Bhi, Blo, bk, bq, EkT, Eq);
  score_kernel<<<4096, 128, 0, stream>>>(Eq, EkT, we, sraw4);
  ctx_fused<<<256, 256, 0, stream>>>(sraw4, value, wout, ctx);
}